// Round 1
// baseline (1039.960 us; speedup 1.0000x reference)
//
#include <hip/hip_runtime.h>
#include <hip/hip_bf16.h>
#include <cstdint>
#include <cstddef>

// Problem constants
#define TT  512
#define BB  256
#define DIN 512
#define HH  128
#define NG  512   // 4*H

typedef __bf16 bf16x8 __attribute__((ext_vector_type(8)));
typedef __bf16 bf16x4 __attribute__((ext_vector_type(4)));
typedef float  f32x4  __attribute__((ext_vector_type(4)));

__device__ __forceinline__ float fast_sig(float x) {
  float e = __builtin_amdgcn_exp2f(-1.44269504f * x);   // e^-x
  return __builtin_amdgcn_rcpf(1.0f + e);
}
__device__ __forceinline__ float fast_tanh(float x) {
  float e = __builtin_amdgcn_exp2f(-2.88539008f * x);   // e^-2x
  return 2.0f * __builtin_amdgcn_rcpf(1.0f + e) - 1.0f;
}

// ---------------- P0: weight transpose + fp32->bf16 convert ----------------
// WiT[n][k] (n<512,k<512), WhT[n][k] (n<512,k<128): k contiguous per row so
// MFMA B-fragments load as 16B vectors.
__global__ void wconv_kernel(const float* __restrict__ Wi, const float* __restrict__ Wh,
                             __bf16* __restrict__ WiT, __bf16* __restrict__ WhT) {
  int idx = blockIdx.x * 256 + threadIdx.x;
  if (idx < DIN * NG) {
    int n = idx >> 9, k = idx & 511;
    WiT[(size_t)n * DIN + k] = (__bf16)Wi[(size_t)k * NG + n];
  }
  if (idx < HH * NG) {
    int n = idx >> 7, k = idx & 127;
    WhT[(size_t)n * HH + k] = (__bf16)Wh[(size_t)k * NG + n];
  }
}

// ---------------- P1: Xg = obs @ Wi + b  (bf16 out, scan-friendly layout) --
// Xg layout: [T][bg=B/16][n=512][bl=16] bf16  (128 MiB)
#define BK 32
__global__ __launch_bounds__(512, 2)
void gemm_kernel(const float* __restrict__ obs, const __bf16* __restrict__ WiT,
                 const float* __restrict__ bias, __bf16* __restrict__ Xg) {
  __shared__ __bf16 Alds[128][BK + 8];   // pad 8 bf16: rows 80B, 16B aligned, ~2-way banks
  __shared__ __bf16 Blds[NG][BK + 8];
  const int tid  = threadIdx.x;
  const int wave = tid >> 6;
  const int lane = tid & 63;
  const int l15  = lane & 15, q = lane >> 4;
  const size_t m0 = (size_t)blockIdx.x * 128;

  const f32x4 fzero = {0.f, 0.f, 0.f, 0.f};
  f32x4 acc[8][4];
#pragma unroll
  for (int i = 0; i < 8; i++)
#pragma unroll
    for (int jj = 0; jj < 4; jj++) acc[i][jj] = fzero;

  const int am = tid >> 2, aq = tid & 3;  // A staging: row, 8-float quarter of BK
  for (int kc = 0; kc < DIN; kc += BK) {
    __syncthreads();
    { // stage A tile 128x32 fp32 -> bf16
      const float* src = obs + (m0 + am) * DIN + kc + aq * 8;
      float4 f0 = ((const float4*)src)[0];
      float4 f1 = ((const float4*)src)[1];
      bf16x8 v = {(__bf16)f0.x, (__bf16)f0.y, (__bf16)f0.z, (__bf16)f0.w,
                  (__bf16)f1.x, (__bf16)f1.y, (__bf16)f1.z, (__bf16)f1.w};
      *(bf16x8*)&Alds[am][aq * 8] = v;
    }
    { // stage B tile 512x32 bf16 (row n = tid, 64B)
      const uint4* src = (const uint4*)(WiT + (size_t)tid * DIN + kc);
      uint4 b0 = src[0], b1 = src[1], b2 = src[2], b3 = src[3];
      uint4* dst = (uint4*)&Blds[tid][0];
      dst[0] = b0; dst[1] = b1; dst[2] = b2; dst[3] = b3;
    }
    __syncthreads();
    bf16x8 bfr[4];
#pragma unroll
    for (int nt = 0; nt < 4; nt++)
      bfr[nt] = *(const bf16x8*)&Blds[wave * 64 + nt * 16 + l15][q * 8];
#pragma unroll
    for (int mt = 0; mt < 8; mt++) {
      bf16x8 af = *(const bf16x8*)&Alds[mt * 16 + l15][q * 8];
#pragma unroll
      for (int nt = 0; nt < 4; nt++)
        acc[mt][nt] = __builtin_amdgcn_mfma_f32_16x16x32_bf16(af, bfr[nt], acc[mt][nt], 0, 0, 0);
    }
  }
  // epilogue: C row = mt*16 + q*4 + r (batch-local), col n = wave*64 + nt*16 + l15
  const int t = blockIdx.x >> 1;             // 2 row-blocks per timestep (256 batch)
  const int bbase = (blockIdx.x & 1) * 128;
#pragma unroll
  for (int mt = 0; mt < 8; mt++) {
    int bloc = bbase + mt * 16 + q * 4;
    int bg = bloc >> 4, bl = bloc & 15;
#pragma unroll
    for (int nt = 0; nt < 4; nt++) {
      int n = wave * 64 + nt * 16 + l15;
      float bb = bias[n];
      bf16x4 v = {(__bf16)(acc[mt][nt][0] + bb), (__bf16)(acc[mt][nt][1] + bb),
                  (__bf16)(acc[mt][nt][2] + bb), (__bf16)(acc[mt][nt][3] + bb)};
      *(bf16x4*)(Xg + (((size_t)t * 16 + bg) * NG + n) * 16 + bl) = v;
    }
  }
}

// ---------------- P2: sequential scan, 16 persistent blocks (1/batch-group) -
// Wave w owns hidden j in [16w,16w+16) for ALL four gates -> i,f,g,o of a
// given (b,j) land in the same lane's accumulators; c-state in registers.
__global__ __launch_bounds__(512, 2)
void scan_kernel(const __bf16* __restrict__ Xg, const __bf16* __restrict__ WhT,
                 const int* __restrict__ done, const float* __restrict__ c0,
                 const float* __restrict__ h0, float* __restrict__ out) {
  __shared__ __bf16 hlds[16][HH + 8];   // rows 272B: 16B aligned, ~2-way banks
  const int tid  = threadIdx.x;
  const int wave = tid >> 6, lane = tid & 63;
  const int l15  = lane & 15, q = lane >> 4;
  const int bg = blockIdx.x, b0 = bg * 16;
  const int j = wave * 16 + l15;

  // Wh B-fragments: resident in registers for the whole scan (64 VGPR/lane)
  bf16x8 bfrag[4][4];
#pragma unroll
  for (int g = 0; g < 4; g++)
#pragma unroll
    for (int ks = 0; ks < 4; ks++)
      bfrag[g][ks] = *(const bf16x8*)(WhT + (size_t)(g * HH + j) * HH + ks * 32 + q * 8);

  bf16x8 zero8;
#pragma unroll
  for (int e = 0; e < 8; e++) zero8[e] = (__bf16)0.0f;
  const f32x4 fzero = {0.f, 0.f, 0.f, 0.f};

  float c_reg[4], nh_reg[4];
#pragma unroll
  for (int r = 0; r < 4; r++) {
    int b = b0 + q * 4 + r;
    c_reg[r] = c0[(size_t)b * HH + j];
    hlds[q * 4 + r][j] = (__bf16)h0[(size_t)b * HH + j];
  }
  __syncthreads();

  // prefetch t=0
  uint2 xg_n[4];
  int dn_n;
#pragma unroll
  for (int g = 0; g < 4; g++)
    xg_n[g] = *(const uint2*)(Xg + ((size_t)bg * NG + g * HH + j) * 16 + q * 4);
  dn_n = done[b0 + l15];

  for (int t = 0; t < TT; t++) {
    uint2 xg_c[4];
#pragma unroll
    for (int g = 0; g < 4; g++) xg_c[g] = xg_n[g];
    int dn_c = dn_n;
    int tn = (t + 1 < TT) ? (t + 1) : t;   // software prefetch next step
#pragma unroll
    for (int g = 0; g < 4; g++)
      xg_n[g] = *(const uint2*)(Xg + (((size_t)tn * 16 + bg) * NG + g * HH + j) * 16 + q * 4);
    dn_n = done[tn * BB + b0 + l15];

    // A-fragments: h state, m = lane&15 (batch-local); done-reset at consumption
    bf16x8 af[4];
#pragma unroll
    for (int ks = 0; ks < 4; ks++)
      af[ks] = *(const bf16x8*)&hlds[l15][ks * 32 + q * 8];
    if (dn_c) {
#pragma unroll
      for (int ks = 0; ks < 4; ks++) af[ks] = zero8;
    }

    f32x4 acc[4];
#pragma unroll
    for (int g = 0; g < 4; g++) {
      acc[g] = fzero;
#pragma unroll
      for (int ks = 0; ks < 4; ks++)
        acc[g] = __builtin_amdgcn_mfma_f32_16x16x32_bf16(af[ks], bfrag[g][ks], acc[g], 0, 0, 0);
    }

#pragma unroll
    for (int r = 0; r < 4; r++) {
      int dnr = __shfl(dn_c, q * 4 + r, 64);  // done for batch row q*4+r
      float cprev = dnr ? 0.0f : c_reg[r];
      union { uint2 u; __bf16 h[4]; } ui, uf2, ug, uo;
      ui.u = xg_c[0]; uf2.u = xg_c[1]; ug.u = xg_c[2]; uo.u = xg_c[3];
      float gi = acc[0][r] + (float)ui.h[r];
      float gf = acc[1][r] + (float)uf2.h[r];
      float gg = acc[2][r] + (float)ug.h[r];
      float go = acc[3][r] + (float)uo.h[r];
      float nc = fast_sig(gf) * cprev + fast_sig(gi) * fast_tanh(gg);
      float nh = fast_sig(go) * fast_tanh(nc);
      c_reg[r] = nc;
      nh_reg[r] = nh;
      out[((size_t)t * BB + b0 + q * 4 + r) * HH + j] = nh;
    }
    __syncthreads();                          // all A-frag reads done
#pragma unroll
    for (int r = 0; r < 4; r++) hlds[q * 4 + r][j] = (__bf16)nh_reg[r];
    __syncthreads();                          // new h visible
  }

  float* cT = out + (size_t)TT * BB * HH;
  float* hT = cT + (size_t)BB * HH;
#pragma unroll
  for (int r = 0; r < 4; r++) {
    cT[(size_t)(b0 + q * 4 + r) * HH + j] = c_reg[r];
    hT[(size_t)(b0 + q * 4 + r) * HH + j] = nh_reg[r];
  }
}

// ---------------- launch ----------------
extern "C" void kernel_launch(void* const* d_in, const int* in_sizes, int n_in,
                              void* d_out, int out_size, void* d_ws, size_t ws_size,
                              hipStream_t stream) {
  const float* c0   = (const float*)d_in[0];
  const float* h0   = (const float*)d_in[1];
  const float* obs  = (const float*)d_in[2];
  const int*   done = (const int*)d_in[3];
  const float* Wi   = (const float*)d_in[4];
  const float* Wh   = (const float*)d_in[5];
  const float* bias = (const float*)d_in[6];
  float* out = (float*)d_out;

  char* ws = (char*)d_ws;
  // ws layout: Xg bf16 [512][16][512][16] = 128 MiB; WiT 512 KiB; WhT 128 KiB
  __bf16* Xg  = (__bf16*)ws;
  __bf16* WiT = (__bf16*)(ws + (size_t)134217728);
  __bf16* WhT = (__bf16*)(ws + (size_t)134217728 + 524288);

  wconv_kernel<<<dim3(1024), dim3(256), 0, stream>>>(Wi, Wh, WiT, WhT);
  gemm_kernel<<<dim3(1024), dim3(512), 0, stream>>>(obs, WiT, bias, Xg);
  scan_kernel<<<dim3(16), dim3(512), 0, stream>>>(Xg, WhT, done, c0, h0, out);
}